// Round 16
// baseline (466.211 us; speedup 1.0000x reference)
//
#include <hip/hip_runtime.h>

#define D 256
#define NC 64

using u16 = unsigned short;
using u32 = unsigned int;

typedef __attribute__((ext_vector_type(8))) short bfv8;   // 8 bf16 = 16 B
typedef __attribute__((ext_vector_type(4))) float f32x4;
typedef __attribute__((ext_vector_type(2))) int v2i;

__device__ __forceinline__ float bf2f(u32 u) {
  union { u32 i; float f; } v; v.i = u << 16; return v.f;
}
__device__ __forceinline__ u16 f2bf(float f) {
  union { float f; u32 i; } v; v.f = f;
  u32 x = v.i;
  return (u16)((x + 0x7FFFu + ((x >> 16) & 1u)) >> 16);  // RTNE
}
__device__ __forceinline__ u32 pk2(float a, float b) {
  return (u32)f2bf(a) | ((u32)f2bf(b) << 16);
}
__device__ __forceinline__ size_t cmrow(int g) {   // class-major row index
  return (size_t)(((g & 63) << 10) | (g >> 6));
}

#define K1_LDS 71168     // gj 71168 ; distp 70144
#define DISTP_LDS 70144  // tile 64K + nfpart 4K (minbuf aliased) + nA 512

// ---------------------------------------------------------------------------
// Blocked Gauss-Jordan inverse (round-9..15 proven body, unchanged).
// ---------------------------------------------------------------------------
__device__ void gj_body(const float* __restrict__ W, float* __restrict__ IW,
                        char* smem) {
  float (*Ml)[20]    = (float(*)[20])smem;                 // 20480 B
  float (*Arow)[256] = (float(*)[256])(smem + 20480);      // 16384 B
  float (*G)[256]    = (float(*)[256])(smem + 36864);      // 16384 B
  u16*  Gfrag        = (u16*)(smem + 53248);               // 16640 B
  float (*Pinv)[20]  = (float(*)[20])(smem + 69888);       // 1280 B
  const int t = threadIdx.x, w = t >> 6, l = t & 63;
  const int lj = l & 15, lh = l >> 4;
  const int r0 = 16 * w;
  const bool lo32 = (l < 32);

  f32x4 x[16];
#pragma unroll
  for (int ct = 0; ct < 16; ++ct)
#pragma unroll
    for (int reg = 0; reg < 4; ++reg)
      x[ct][reg] = W[(size_t)(r0 + 4 * lh + reg) * D + 16 * ct + lj];

  for (int s = 0; s < 16; ++s) {
#pragma unroll
    for (int ct = 0; ct < 16; ++ct)
      if (ct == s)
#pragma unroll
        for (int reg = 0; reg < 4; ++reg)
          Ml[r0 + 4 * lh + reg][lj] = x[ct][reg];
    if (w == s) {
#pragma unroll
      for (int ct = 0; ct < 16; ++ct)
#pragma unroll
        for (int reg = 0; reg < 4; ++reg)
          Arow[4 * lh + reg][16 * ct + lj] = x[ct][reg];
    }
    bfv8 afr;
    {
      const int row = r0 + lj;
      float4 f0 = *(const float4*)&Ml[row][8 * (lh & 1)];
      float4 f1 = *(const float4*)&Ml[row][8 * (lh & 1) + 4];
      const float fv[8] = {f0.x, f0.y, f0.z, f0.w, f1.x, f1.y, f1.z, f1.w};
      union { bfv8 v; u16 e[8]; } A;
      if (lh < 2) {
#pragma unroll
        for (int e = 0; e < 8; ++e) A.e[e] = f2bf(-fv[e]);
      } else {
#pragma unroll
        for (int e = 0; e < 8; ++e) {
          const float hi = bf2f(f2bf(fv[e]));
          A.e[e] = f2bf(-(fv[e] - hi));
        }
      }
      afr = A.v;
    }
    __syncthreads();
    if (t < 16) {
      float p[16];
      {
        float4 rr0 = *(const float4*)&Ml[16 * s + t][0];
        float4 rr1 = *(const float4*)&Ml[16 * s + t][4];
        float4 rr2 = *(const float4*)&Ml[16 * s + t][8];
        float4 rr3 = *(const float4*)&Ml[16 * s + t][12];
        p[0] = rr0.x; p[1] = rr0.y; p[2] = rr0.z; p[3] = rr0.w;
        p[4] = rr1.x; p[5] = rr1.y; p[6] = rr1.z; p[7] = rr1.w;
        p[8] = rr2.x; p[9] = rr2.y; p[10] = rr2.z; p[11] = rr2.w;
        p[12] = rr3.x; p[13] = rr3.y; p[14] = rr3.z; p[15] = rr3.w;
      }
#pragma unroll
      for (int pp = 0; pp < 16; ++pp) {
        float u[16];
#pragma unroll
        for (int j = 0; j < 16; ++j)
          u[j] = __int_as_float(__builtin_amdgcn_readlane(__float_as_int(p[j]), pp));
        const float pv = u[pp];
        const float d = 1.0f / pv;
        if (t == pp) {
#pragma unroll
          for (int j = 0; j < 16; ++j) p[j] = u[j] * d;
          p[pp] = d;
        } else {
          const float md = p[pp] * d;
          u[pp] = pv + 1.0f;
#pragma unroll
          for (int j = 0; j < 16; ++j) p[j] = fmaf(-md, u[j], p[j]);
        }
      }
#pragma unroll
      for (int j = 0; j < 16; ++j) Pinv[t][j] = p[j];
    }
    __syncthreads();
    {
      const bool inC = ((l >> 2) == s);
      const int co = (l & 3) << 2;
      const int gct = l >> 2;
      const int kk = w;
      float4 g = make_float4(0.f, 0.f, 0.f, 0.f);
#pragma unroll
      for (int q = 0; q < 16; ++q) {
        const float pv = Pinv[kk][q];
        const float4 av = *(const float4*)&Arow[q][4 * l];
        g.x = fmaf(pv, av.x, g.x); g.y = fmaf(pv, av.y, g.y);
        g.z = fmaf(pv, av.z, g.z); g.w = fmaf(pv, av.w, g.w);
      }
      if (inC) {
        g.x = Pinv[kk][co + 0] + (kk == co + 0 ? 1.f : 0.f);
        g.y = Pinv[kk][co + 1] + (kk == co + 1 ? 1.f : 0.f);
        g.z = Pinv[kk][co + 2] + (kk == co + 2 ? 1.f : 0.f);
        g.w = Pinv[kk][co + 3] + (kk == co + 3 ? 1.f : 0.f);
      }
      *(float4*)&G[kk][4 * l] = g;
      const int e0 = kk & 7;
      const int lbase = 16 * (kk >> 3);
      const float gv[4] = {g.x, g.y, g.z, g.w};
#pragma unroll
      for (int cc = 0; cc < 4; ++cc) {
        const int cl = 4 * (l & 3) + cc;
        const u16 hi = f2bf(gv[cc]);
        const u16 lo = f2bf(gv[cc] - bf2f(hi));
        Gfrag[gct * 520 + (lbase + cl) * 8 + e0] = hi;
        Gfrag[gct * 520 + (32 + lbase + cl) * 8 + e0] = lo;
      }
    }
    __syncthreads();
    if (w != s) {
#pragma unroll
      for (int ct = 0; ct < 16; ++ct) {
        union { bfv8 v; uint4 u; } B1, B2;
        B1.v = *(const bfv8*)&Gfrag[ct * 520 + l * 8];
#if __has_builtin(__builtin_amdgcn_permlane32_swap)
        {
          v2i r;
          r = __builtin_amdgcn_permlane32_swap((int)B1.u.x, (int)B1.u.x, false, false);
          B2.u.x = lo32 ? (u32)r.y : (u32)r.x;
          r = __builtin_amdgcn_permlane32_swap((int)B1.u.y, (int)B1.u.y, false, false);
          B2.u.y = lo32 ? (u32)r.y : (u32)r.x;
          r = __builtin_amdgcn_permlane32_swap((int)B1.u.z, (int)B1.u.z, false, false);
          B2.u.z = lo32 ? (u32)r.y : (u32)r.x;
          r = __builtin_amdgcn_permlane32_swap((int)B1.u.w, (int)B1.u.w, false, false);
          B2.u.w = lo32 ? (u32)r.y : (u32)r.x;
        }
#else
        B2.v = *(const bfv8*)&Gfrag[ct * 520 + (l ^ 32) * 8];
#endif
        x[ct] = __builtin_amdgcn_mfma_f32_16x16x32_bf16(afr, B1.v, x[ct], 0, 0, 0);
        x[ct] = __builtin_amdgcn_mfma_f32_16x16x32_bf16(afr, B2.v, x[ct], 0, 0, 0);
      }
    } else {
#pragma unroll
      for (int ct = 0; ct < 16; ++ct) {
        if (ct == s) {
#pragma unroll
          for (int reg = 0; reg < 4; ++reg)
            x[ct][reg] = Pinv[4 * lh + reg][lj];
        } else {
#pragma unroll
          for (int reg = 0; reg < 4; ++reg)
            x[ct][reg] = G[4 * lh + reg][16 * ct + lj];
        }
      }
    }
    __syncthreads();
  }
#pragma unroll
  for (int ct = 0; ct < 16; ++ct)
#pragma unroll
    for (int reg = 0; reg < 4; ++reg)
      IW[(size_t)(r0 + 4 * lh + reg) * D + 16 * ct + lj] = x[ct][reg];
}

// ---------------------------------------------------------------------------
// convnorm: f32 row-major -> bf16 class-major + exact f32 row norms.
// ---------------------------------------------------------------------------
__device__ void convnorm_role(const float* __restrict__ P, u16* __restrict__ Pb,
                              float* __restrict__ nrm, int blk) {
  const int tx = threadIdx.x;
  const int r = tx >> 2, q = tx & 3;
  const int g = blk * 256 + r;
  const float* src = P + (size_t)g * D + q * 64;
  u16* dst = Pb + cmrow(g) * D + q * 64;
  float ss = 0.f;
#pragma unroll
  for (int g4 = 0; g4 < 8; ++g4) {
    float4 v0 = *(const float4*)(src + g4 * 8);
    float4 v1 = *(const float4*)(src + g4 * 8 + 4);
    ss = fmaf(v0.x, v0.x, fmaf(v0.y, v0.y, fmaf(v0.z, v0.z, fmaf(v0.w, v0.w, ss))));
    ss = fmaf(v1.x, v1.x, fmaf(v1.y, v1.y, fmaf(v1.z, v1.z, fmaf(v1.w, v1.w, ss))));
    uint4 w4;
    w4.x = pk2(v0.x, v0.y); w4.y = pk2(v0.z, v0.w);
    w4.z = pk2(v1.x, v1.y); w4.w = pk2(v1.z, v1.w);
    *(uint4*)(dst + g4 * 8) = w4;
  }
  ss += __shfl_xor(ss, 1, 64);
  ss += __shfl_xor(ss, 2, 64);
  if (q == 0) nrm[cmrow(g)] = ss;
}

// ---------------------------------------------------------------------------
// distp v3: tile prep (proven, full __syncthreads) + dist loop with B-frags
// loaded GLOBAL->REG per wave (compiler-counted vmcnt; no LDS panel, no DMA)
// and raw lgkm-only barriers (vmem pipe free-runs across barriers).
// ---------------------------------------------------------------------------
template <int MODE>
__device__ void distp_body(const float* __restrict__ Pj,
                           const u16* __restrict__ Brows,
                           const float* __restrict__ biasv,
                           const u16* __restrict__ PanBF,
                           const float* __restrict__ nB,
                           float* __restrict__ pmind, int bid, char* smem) {
  const int lb = (bid & 7) * 64 + (bid >> 3);   // XCD swizzle: class->XCD
  const int c = lb >> 3, jt = lb & 7;
  const int tx = threadIdx.x, ww = tx >> 6, l = tx & 63;
  const int mw = ww >> 3, nw = ww & 7, l4 = l >> 4, lm = l & 15;
  char* Ab = smem;                          // A-stage -> tile (LDS)
  float* nfpart = (float*)(smem + 65536);   // [8][128] (tile-store phase)
  float* minbuf = (float*)(smem + 65536);   // [2][4][64] ping-pong (aliased)
  float* nAb = (float*)(smem + 69632);      // [128]

  // ---- B frags from bf16 Brows (global, L2-hot)
  bfv8 bfr[2][8];
#pragma unroll
  for (int nf2 = 0; nf2 < 2; ++nf2)
#pragma unroll
    for (int ks = 0; ks < 8; ++ks)
      bfr[nf2][ks] = *(const bfv8*)(Brows +
          (size_t)(nw * 32 + nf2 * 16 + lm) * D + ks * 32 + l4 * 8);
  // ---- A staging: class-gathered f32 rows -> bf16 frags in LDS
  {
    const int r = tx >> 3, sg = tx & 7;
    const float* arow = Pj + ((size_t)(jt * 128 + r) * NC + c) * D + sg * 32;
#pragma unroll
    for (int g2 = 0; g2 < 4; ++g2) {
      float4 v0 = *(const float4*)(arow + g2 * 8);
      float4 v1 = *(const float4*)(arow + g2 * 8 + 4);
      uint4 w4;
      w4.x = pk2(v0.x, v0.y); w4.y = pk2(v0.z, v0.w);
      w4.z = pk2(v1.x, v1.y); w4.w = pk2(v1.z, v1.w);
      *(uint4*)(Ab + (sg * 8 + (r >> 4)) * 1024 + ((r & 15) + g2 * 16) * 16) = w4;
    }
  }
  __syncthreads();
  const bfv8* A8 = (const bfv8*)Ab;
  f32x4 acc[4][2];
#pragma unroll
  for (int mf = 0; mf < 4; ++mf) {
    acc[mf][0] = f32x4{0.f, 0.f, 0.f, 0.f};
    acc[mf][1] = f32x4{0.f, 0.f, 0.f, 0.f};
  }
#pragma unroll
  for (int ks = 0; ks < 8; ++ks)
#pragma unroll
    for (int mf = 0; mf < 4; ++mf) {
      bfv8 a = A8[(ks * 8 + mw * 4 + mf) * 64 + l];
      acc[mf][0] = __builtin_amdgcn_mfma_f32_16x16x32_bf16(a, bfr[0][ks], acc[mf][0], 0, 0, 0);
      acc[mf][1] = __builtin_amdgcn_mfma_f32_16x16x32_bf16(a, bfr[1][ks], acc[mf][1], 0, 0, 0);
    }
  float bias[2];
  if (MODE == 0) {
#pragma unroll
    for (int nf2 = 0; nf2 < 2; ++nf2)
      bias[nf2] = biasv[nw * 32 + nf2 * 16 + lm];
  } else {
#pragma unroll
    for (int nf2 = 0; nf2 < 2; ++nf2) {
      float pd = 0.f;
#pragma unroll
      for (int ks = 0; ks < 8; ++ks) {
        float4 b0 = *(const float4*)(biasv + ks * 32 + l4 * 8);
        float4 b1 = *(const float4*)(biasv + ks * 32 + l4 * 8 + 4);
        pd = fmaf(b0.x, bf2f((u16)bfr[nf2][ks][0]), pd);
        pd = fmaf(b0.y, bf2f((u16)bfr[nf2][ks][1]), pd);
        pd = fmaf(b0.z, bf2f((u16)bfr[nf2][ks][2]), pd);
        pd = fmaf(b0.w, bf2f((u16)bfr[nf2][ks][3]), pd);
        pd = fmaf(b1.x, bf2f((u16)bfr[nf2][ks][4]), pd);
        pd = fmaf(b1.y, bf2f((u16)bfr[nf2][ks][5]), pd);
        pd = fmaf(b1.z, bf2f((u16)bfr[nf2][ks][6]), pd);
        pd = fmaf(b1.w, bf2f((u16)bfr[nf2][ks][7]), pd);
      }
      pd += __shfl_xor(pd, 16, 64);
      pd += __shfl_xor(pd, 32, 64);
      bias[nf2] = -pd;
    }
  }
  __syncthreads();   // all MFMA reads of Ab done before tile overwrite
  // ---- store computed tile to LDS (A-frag order) + rounded row norms
  u16* tile = (u16*)Ab;
#pragma unroll
  for (int mf = 0; mf < 4; ++mf)
#pragma unroll
    for (int rr = 0; rr < 4; ++rr) {
      const int j = mw * 64 + mf * 16 + l4 * 4 + rr;
      float v2 = 0.f;
#pragma unroll
      for (int nf2 = 0; nf2 < 2; ++nf2) {
        const float v = acc[mf][nf2][rr] + bias[nf2];
        const u16 hv = f2bf(v);
        tile[(((nw * 8 + mw * 4 + mf) << 6) + ((nf2 * 2 + (lm >> 3)) << 4)
              + l4 * 4 + rr) * 8 + (lm & 7)] = hv;
        const float vr = bf2f(hv);
        v2 = fmaf(vr, vr, v2);
      }
      v2 += __shfl_xor(v2, 1, 64);
      v2 += __shfl_xor(v2, 2, 64);
      v2 += __shfl_xor(v2, 4, 64);
      v2 += __shfl_xor(v2, 8, 64);
      if (lm == 0) nfpart[nw * 128 + j] = v2;
    }
  __syncthreads();   // tile visible to all
  // ---- load this wave's A-slice to registers
  const int jw = ww >> 2, iw = ww & 3;
  bfv8 afr[2][8];
#pragma unroll
  for (int jj = 0; jj < 2; ++jj)
#pragma unroll
    for (int ks = 0; ks < 8; ++ks)
      afr[jj][ks] = A8[(ks * 8 + jw * 2 + jj) * 64 + l];
  __syncthreads();
  if (tx < 128) {
    float s = 0.f;
#pragma unroll
    for (int q = 0; q < 8; ++q) s += nfpart[q * 128 + tx];
    nAb[tx] = s;
  }
  __syncthreads();   // nAb ready; nfpart dead (minbuf aliases it)
  // ---- distance loop over 16 i-chunks of 64; B global->reg per wave.
  // Only cross-wave state: minbuf (LDS, ping-pong). Raw barrier + lgkm-only
  // drain: the vmem pipe (B loads, pmind stores) free-runs across barriers.
  const float* nBc = nB + (c << 10);
  const size_t obase = (size_t)(c * 8 + jt) * 1024;
  const u16* pb = PanBF + ((size_t)(c << 10) + iw * 16 + lm) * D + l4 * 8;
  for (int ch = 0; ch < 16; ++ch) {
    bfv8 b[8];
#pragma unroll
    for (int ks = 0; ks < 8; ++ks)
      b[ks] = *(const bfv8*)(pb + (size_t)ch * 64 * D + ks * 32);
    f32x4 a2[2];
    a2[0] = f32x4{0.f, 0.f, 0.f, 0.f};
    a2[1] = f32x4{0.f, 0.f, 0.f, 0.f};
#pragma unroll
    for (int ks = 0; ks < 8; ++ks) {
      a2[0] = __builtin_amdgcn_mfma_f32_16x16x32_bf16(afr[0][ks], b[ks], a2[0], 0, 0, 0);
      a2[1] = __builtin_amdgcn_mfma_f32_16x16x32_bf16(afr[1][ks], b[ks], a2[1], 0, 0, 0);
    }
    const float nb = nBc[ch * 64 + iw * 16 + lm];
    float mm = 3.0e38f;
#pragma unroll
    for (int jj = 0; jj < 2; ++jj)
#pragma unroll
      for (int rr = 0; rr < 4; ++rr) {
        const float dd = nb + nAb[jw * 32 + jj * 16 + l4 * 4 + rr]
                         - 2.0f * a2[jj][rr];
        mm = fminf(mm, dd);
      }
    mm = fminf(mm, __shfl_xor(mm, 16, 64));
    mm = fminf(mm, __shfl_xor(mm, 32, 64));
    float* mb = minbuf + (ch & 1) * 256;
    if (l4 == 0) mb[jw * 64 + iw * 16 + lm] = mm;
    // raw barrier: drain LDS only (minbuf write), keep vmem in flight
    asm volatile("s_waitcnt lgkmcnt(0)" ::: "memory");
    __builtin_amdgcn_s_barrier();
    asm volatile("" ::: "memory");
    __builtin_amdgcn_sched_barrier(0);
    if (tx < 64) {
      float m = mb[tx];
#pragma unroll
      for (int q = 1; q < 4; ++q) m = fminf(m, mb[q * 64 + tx]);
      pmind[obase + ch * 64 + tx] = m;
    }
    // WAR on this minbuf bank: rewritten at ch+2, after the ch+1 barrier,
    // which the reader must pass first (ping-pong, proven in r15).
  }
}

// K0: blocks 0..255 = convnorm(p2 -> p2b, n2); block 256 = W -> bf16 Wb
__global__ __launch_bounds__(1024, 1) void k0_kernel(
    const float* __restrict__ p2, u16* __restrict__ p2b,
    float* __restrict__ n2, const float* __restrict__ W,
    u16* __restrict__ Wb) {
  if (blockIdx.x < 256) {
    convnorm_role(p2, p2b, n2, blockIdx.x);
  } else {
    const int t = threadIdx.x;
#pragma unroll
    for (int k = 0; k < 64; ++k) Wb[k * 1024 + t] = f2bf(W[k * 1024 + t]);
  }
}

// K1: block 0 = gj; 1..512 = dist dir=1 (F in-block from Wb, panel p2b);
// 513..768 = convnorm p1 -> p1b, n1 (for K3).
__global__ __launch_bounds__(1024, 1) void k1_kernel(
    const float* __restrict__ p1, const float* __restrict__ W,
    const u16* __restrict__ Wb, const float* __restrict__ bv,
    const u16* __restrict__ p2b, const float* __restrict__ n2,
    float* __restrict__ pmin1, float* __restrict__ IWa,
    u16* __restrict__ p1b, float* __restrict__ n1) {
  extern __shared__ char smem[];
  const int b = blockIdx.x;
  if (b == 0) {
    gj_body(W, IWa, smem);
  } else if (b <= 512) {
    distp_body<0>(p1, Wb, bv, p2b, n2, pmin1, b - 1, smem);
  } else {
    convnorm_role(p1, p1b, n1, b - 513);
  }
}

// Fused Newton-Schulz: Y = X(2I - W X) -> bf16. 32 blocks x 8 columns.
__global__ __launch_bounds__(256) void ns_fused(const float* __restrict__ W,
                                                const float* __restrict__ X,
                                                u16* __restrict__ Yb) {
  __shared__ float Xc[256][8];
  __shared__ float Rc[256][8];
  const int jc = blockIdx.x * 8, t = threadIdx.x;
  {
    float4 xa = *(const float4*)&X[(size_t)t * D + jc];
    float4 xb = *(const float4*)&X[(size_t)t * D + jc + 4];
    Xc[t][0] = xa.x; Xc[t][1] = xa.y; Xc[t][2] = xa.z; Xc[t][3] = xa.w;
    Xc[t][4] = xb.x; Xc[t][5] = xb.y; Xc[t][6] = xb.z; Xc[t][7] = xb.w;
  }
  __syncthreads();
  float r[8] = {0.f, 0.f, 0.f, 0.f, 0.f, 0.f, 0.f, 0.f};
#pragma unroll 4
  for (int k = 0; k < D; ++k) {
    const float wv = W[(size_t)t * D + k];
#pragma unroll
    for (int q = 0; q < 8; ++q) r[q] = fmaf(wv, Xc[k][q], r[q]);
  }
#pragma unroll
  for (int q = 0; q < 8; ++q)
    Rc[t][q] = ((t - jc) == q ? 2.0f : 0.0f) - r[q];
  __syncthreads();
  float y[8] = {0.f, 0.f, 0.f, 0.f, 0.f, 0.f, 0.f, 0.f};
#pragma unroll 4
  for (int k = 0; k < D; ++k) {
    const float xv = X[(size_t)t * D + k];
#pragma unroll
    for (int q = 0; q < 8; ++q) y[q] = fmaf(xv, Rc[k][q], y[q]);
  }
#pragma unroll
  for (int q = 0; q < 8; ++q)
    Yb[(size_t)t * D + jc + q] = f2bf(y[q]);
}

// K3: dist dir=0 (Q in-block from IWb; panel p1b + norms n1)
__global__ __launch_bounds__(1024, 1) void k3_kernel(
    const float* __restrict__ p2, const u16* __restrict__ IWb,
    const float* __restrict__ bv, const u16* __restrict__ p1b,
    const float* __restrict__ n1, float* __restrict__ pmin0) {
  extern __shared__ char smem[];
  distp_body<1>(p2, IWb, bv, p1b, n1, pmin0, blockIdx.x, smem);
}

// final: out[dir*64+c] = mean_i min_jt pmin[dir][c][jt][i]
__global__ __launch_bounds__(256) void final_kernel(const float* __restrict__ pmin,
                                                    float* __restrict__ out) {
  __shared__ float ws4[4];
  const int dc = blockIdx.x, tx = threadIdx.x;
  const float* base = pmin + (size_t)dc * 8192;
  float s = 0.f;
#pragma unroll
  for (int t = 0; t < 4; ++t) {
    const int i = t * 256 + tx;
    float m = base[i];
#pragma unroll
    for (int j = 1; j < 8; ++j) m = fminf(m, base[j * 1024 + i]);
    s += m;
  }
#pragma unroll
  for (int off = 32; off; off >>= 1) s += __shfl_xor(s, off, 64);
  if ((tx & 63) == 0) ws4[tx >> 6] = s;
  __syncthreads();
  if (tx == 0)
    out[dc] = (ws4[0] + ws4[1] + ws4[2] + ws4[3]) * (1.0f / 1024.0f);
}

extern "C" void kernel_launch(void* const* d_in, const int* in_sizes, int n_in,
                              void* d_out, int out_size, void* d_ws, size_t ws_size,
                              hipStream_t stream) {
  const float* p1 = (const float*)d_in[0];
  const float* p2 = (const float*)d_in[1];
  const float* W  = (const float*)d_in[2];
  const float* bv = (const float*)d_in[3];
  float* out = (float*)d_out;
  char* ws = (char*)d_ws;
  float* n1  = (float*)(ws);                     // 256KB
  float* n2  = (float*)(ws + (256 << 10));       // 256KB
  u16* Wb    = (u16*)(ws + (512 << 10));         // 128KB
  u16* IWb   = (u16*)(ws + (640 << 10));         // 128KB
  float* IWa = (float*)(ws + (768 << 10));       // 256KB
  float* pmin = (float*)(ws + (1 << 20));        // 4MB: [dir][c][jt][1024]
  u16* p1b   = (u16*)(ws + (6u << 20));          // 32MB class-major bf16
  u16* p2b   = (u16*)(ws + (38u << 20));         // 32MB
  float* pmin0 = pmin;                 // dir 0 (source: p1 vs Q)
  float* pmin1 = pmin + 524288;        // dir 1 (target: p2 vs F)

  hipFuncSetAttribute((const void*)k1_kernel,
                      hipFuncAttributeMaxDynamicSharedMemorySize, K1_LDS);
  hipFuncSetAttribute((const void*)k3_kernel,
                      hipFuncAttributeMaxDynamicSharedMemorySize, DISTP_LDS);

  // K0: p2 convert + norms, W -> bf16
  k0_kernel<<<257, 1024, 0, stream>>>(p2, p2b, n2, W, Wb);
  // K1: gj inverse || dist dir=1 || p1 convert + norms
  k1_kernel<<<769, 1024, K1_LDS, stream>>>(p1, W, Wb, bv, p2b, n2,
                                           pmin1, IWa, p1b, n1);
  // fused Newton-Schulz refinement, bf16 output
  ns_fused<<<32, 256, 0, stream>>>(W, IWa, IWb);
  // K3: dist dir=0 (Q from IWb)
  k3_kernel<<<512, 1024, DISTP_LDS, stream>>>(p2, IWb, bv, p1b, n1, pmin0);
  final_kernel<<<128, 256, 0, stream>>>(pmin, out);
}